// Round 4
// baseline (349.270 us; speedup 1.0000x reference)
//
#include <hip/hip_runtime.h>
#include <hip/hip_bf16.h>

// Problem: B=16, N=1024, EMB=128, H=8, INNER=1024
// out = proj( attention( LN(x) @ Wqkv ) ) + b_proj,  fp32 in/out, bf16-tolerance.

typedef __attribute__((ext_vector_type(8))) short bf16x8;
typedef __attribute__((ext_vector_type(4))) float f32x4;

__device__ __forceinline__ unsigned short f2bf(float f) {
  unsigned int u = __float_as_uint(f);
  u += 0x7FFF + ((u >> 16) & 1);   // round-nearest-even
  return (unsigned short)(u >> 16);
}

// async global->LDS, 16B per lane; LDS dest = wave-uniform base + lane*16
__device__ __forceinline__ void gll16(const void* g, void* l) {
  __builtin_amdgcn_global_load_lds((const __attribute__((address_space(1))) unsigned int*)g,
                                   (__attribute__((address_space(3))) unsigned int*)l, 16, 0, 0);
}

// ---------------- LayerNorm + bf16 cast: one wave per 128-elem row ----------
__global__ __launch_bounds__(256) void k_ln(const float* __restrict__ x,
                                            const float* __restrict__ gamma,
                                            const float* __restrict__ beta,
                                            unsigned short* __restrict__ xb) {
  int row  = blockIdx.x * 4 + (threadIdx.x >> 6);
  int lane = threadIdx.x & 63;
  float2 v = *reinterpret_cast<const float2*>(x + row * 128 + lane * 2);
  float s = v.x + v.y, ss = v.x * v.x + v.y * v.y;
#pragma unroll
  for (int m = 1; m < 64; m <<= 1) { s += __shfl_xor(s, m); ss += __shfl_xor(ss, m); }
  float mu   = s * (1.0f / 128.0f);
  float var  = ss * (1.0f / 128.0f) - mu * mu;
  float rstd = rsqrtf(var + 1e-5f);
  float2 g  = *reinterpret_cast<const float2*>(gamma + lane * 2);
  float2 be = *reinterpret_cast<const float2*>(beta + lane * 2);
  ushort2 o;
  o.x = f2bf((v.x - mu) * rstd * g.x + be.x);
  o.y = f2bf((v.y - mu) * rstd * g.y + be.y);
  *reinterpret_cast<ushort2*>(xb + row * 128 + lane * 2) = o;
}

// ------------- cast + transpose w_qkv [128][3072] -> [3072][128] bf16 -------
// LDS-tiled: coalesced reads AND writes.
__global__ __launch_bounds__(256) void k_cast_wqkv(const float* __restrict__ w,
                                                   unsigned short* __restrict__ wt) {
  __shared__ unsigned short T[128][70];
  const int n0 = blockIdx.x * 64;
  const int tid = threadIdx.x;
#pragma unroll
  for (int i = 0; i < 32; i++) {
    int idx = i * 256 + tid;
    int k = idx >> 6, c = idx & 63;
    T[k][c] = f2bf(w[k * 3072 + n0 + c]);
  }
  __syncthreads();
#pragma unroll
  for (int i = 0; i < 32; i++) {
    int idx = i * 256 + tid;
    int n = idx >> 7, k = idx & 127;
    wt[(n0 + n) * 128 + k] = T[k][n];
  }
}

// ------------- cast + transpose w_proj [1024][128] -> [128][1024] bf16 ------
__global__ __launch_bounds__(256) void k_cast_wproj(const float* __restrict__ w,
                                                    unsigned short* __restrict__ wt) {
  __shared__ unsigned short T[128][134];
  const int k0 = blockIdx.x * 128;
  const int tid = threadIdx.x;
#pragma unroll
  for (int i = 0; i < 64; i++) {
    int idx = i * 256 + tid;
    int r = idx >> 7, c = idx & 127;
    T[r][c] = f2bf(w[(k0 + r) * 128 + c]);
  }
  __syncthreads();
#pragma unroll
  for (int i = 0; i < 64; i++) {
    int idx = i * 256 + tid;
    int c = idx >> 7, r = idx & 127;
    wt[c * 1024 + k0 + r] = T[r][c];
  }
}

// ------------- QKV GEMM: [16384,128] @ [128,3072]; writes Q,K [B,H,N,D], Vt [B,H,D,N]
// gll staging, swizzled LDS (slot ^= row&7), single stage (K=128), one barrier.
__global__ __launch_bounds__(256) void k_qkv(const unsigned short* __restrict__ xb,
                                             const unsigned short* __restrict__ wt,  // [3072][128]
                                             unsigned short* __restrict__ qb,
                                             unsigned short* __restrict__ kb,
                                             unsigned short* __restrict__ vtb) {
  __shared__ __align__(16) unsigned short Xs[128][128];
  __shared__ __align__(16) unsigned short Ws[128][128];
  const int m0 = blockIdx.x * 128;
  const int n0 = blockIdx.y * 128;
  const int tid = threadIdx.x, wave = tid >> 6, lane = tid & 63;
  const int lm = lane & 15, lg = lane >> 4;
  const int wr = wave >> 1, wc = wave & 1;

#pragma unroll
  for (int ii = 0; ii < 8; ii++) {
    int row = wave * 32 + ii * 4 + (lane >> 4);
    int c = (lane & 15) ^ (row & 7);
    gll16(xb + (m0 + row) * 128 + c * 8, &Xs[wave * 32 + ii * 4][0]);
    gll16(wt + (n0 + row) * 128 + c * 8, &Ws[wave * 32 + ii * 4][0]);
  }
  __syncthreads();

  f32x4 acc[4][4];
#pragma unroll
  for (int i = 0; i < 4; i++)
#pragma unroll
    for (int j = 0; j < 4; j++) acc[i][j] = {0.f, 0.f, 0.f, 0.f};

#pragma unroll
  for (int k32 = 0; k32 < 4; k32++) {
    bf16x8 af[4], bfr[4];
#pragma unroll
    for (int mi = 0; mi < 4; mi++) {
      int row = wr * 64 + mi * 16 + lm;
      af[mi] = *(const bf16x8*)((const char*)&Xs[row][0] + ((k32 * 64 + lg * 16) ^ ((lm & 7) << 4)));
    }
#pragma unroll
    for (int ni = 0; ni < 4; ni++) {
      int row = wc * 64 + ni * 16 + lm;
      bfr[ni] = *(const bf16x8*)((const char*)&Ws[row][0] + ((k32 * 64 + lg * 16) ^ ((lm & 7) << 4)));
    }
#pragma unroll
    for (int mi = 0; mi < 4; mi++)
#pragma unroll
      for (int ni = 0; ni < 4; ni++)
        acc[mi][ni] = __builtin_amdgcn_mfma_f32_16x16x32_bf16(af[mi], bfr[ni], acc[mi][ni], 0, 0, 0);
  }

  // epilogue: n<1024 -> Q (scaled by (1/32)*log2(e) for exp2 softmax), n<2048 -> K, else V^T
#pragma unroll
  for (int mi = 0; mi < 4; mi++)
#pragma unroll
    for (int ni = 0; ni < 4; ni++)
#pragma unroll
      for (int j = 0; j < 4; j++) {
        int m = m0 + wr * 64 + mi * 16 + 4 * (lane >> 4) + j;
        int n = n0 + wc * 64 + ni * 16 + lm;
        float val = acc[mi][ni][j];
        int bb = m >> 10, seq = m & 1023;
        int sel = n >> 10, r = n & 1023, h = r >> 7, d = r & 127;
        int bh = bb * 8 + h;
        if (sel == 0)      qb[(bh * 1024 + seq) * 128 + d] = f2bf(val * 0.04508422f);
        else if (sel == 1) kb[(bh * 1024 + seq) * 128 + d] = f2bf(val);
        else               vtb[(bh * 128 + d) * 1024 + seq] = f2bf(val);
      }
}

// ------------- flash attention, swapped-QK^T, K gll-dbuf in LDS, V direct ---
// grid: 2048 blocks; bi -> (bh, qtile) with same-bh blocks on one XCD.
__global__ __launch_bounds__(256, 3) void k_flash(const unsigned short* __restrict__ qb,
                                                  const unsigned short* __restrict__ kb,
                                                  const unsigned short* __restrict__ vtb,
                                                  unsigned short* __restrict__ ob) {
  __shared__ __align__(16) unsigned short Ks[2][64][128];    // [key][d], swizzled slots
  __shared__ __align__(16) unsigned short Ps[4][16][72];     // per-wave P: [q][k]
  const int bi = blockIdx.x;
  const int bh = ((bi >> 7) << 3) | (bi & 7);                // XCD = bi%8 = bh%8
  const int q0 = ((bi >> 3) & 15) * 64;
  const int tid = threadIdx.x, wave = tid >> 6, lane = tid & 63;
  const int lm = lane & 15, lg = lane >> 4, lk8 = lg * 8;
  const int b = bh >> 3, h = bh & 7;

  const unsigned short* kbh = kb + bh * 1024 * 128;
  const unsigned short* vlane = vtb + bh * 128 * 1024 + lm * 1024 + lk8;  // V^T row base

  // Q^T B-fragments (q pre-scaled by (1/32)*log2e in k_qkv)
  bf16x8 aq[4];
  const unsigned short* qrow = qb + (bh * 1024 + q0 + wave * 16 + lm) * 128;
#pragma unroll
  for (int kc = 0; kc < 4; kc++) aq[kc] = *(const bf16x8*)(qrow + kc * 32 + lk8);

  f32x4 oacc[8];                                             // O^T[d=16dt+4lg+j][q=lm]
#pragma unroll
  for (int dt = 0; dt < 8; dt++) oacc[dt] = {0.f, 0.f, 0.f, 0.f};
  float mrun = -3e38f, lrun = 0.f;

  auto stageK = [&](int kt, int buf) {
#pragma unroll
    for (int ii = 0; ii < 4; ii++) {             // K tile: 64 rows x 256B
      int krow = wave * 16 + ii * 4 + (lane >> 4);
      int c = (lane & 15) ^ (krow & 7);
      gll16(kbh + (kt * 64 + krow) * 128 + c * 8, &Ks[buf][wave * 16 + ii * 4][0]);
    }
  };

  stageK(0, 0);
  __syncthreads();
  int cur = 0;

  for (int kt = 0; kt < 16; kt++) {
    if (kt < 15) stageK(kt + 1, cur ^ 1);        // async prefetch into other buffer
    __builtin_amdgcn_sched_barrier(0);           // keep gll issue ahead of compute

    // S^T = K · Q^T : lane holds S^T[16nt+4lg+j][q=lm]  (log2 domain)
    f32x4 sc[4];
    __builtin_amdgcn_s_setprio(1);
#pragma unroll
    for (int nt = 0; nt < 4; nt++) {
      f32x4 a = {0.f, 0.f, 0.f, 0.f};
      const char* krowp = (const char*)&Ks[cur][nt * 16 + lm][0];
#pragma unroll
      for (int kc = 0; kc < 4; kc++) {
        bf16x8 ak = *(const bf16x8*)(krowp + ((kc * 64 + lg * 16) ^ ((lm & 7) << 4)));
        a = __builtin_amdgcn_mfma_f32_16x16x32_bf16(ak, aq[kc], a, 0, 0, 0);
      }
      sc[nt] = a;
    }
    __builtin_amdgcn_s_setprio(0);

    // prefetch V^T fragments for this kt (L1/L2-hot); latency hides under softmax
    bf16x8 av[2][8];
#pragma unroll
    for (int t = 0; t < 2; t++)
#pragma unroll
      for (int dt = 0; dt < 8; dt++)
        av[t][dt] = *(const bf16x8*)(vlane + dt * 16384 + kt * 64 + t * 32);

    // online softmax, base-2, defer-max (THR=8): rescale only on real max growth
    float mx16 = fmaxf(fmaxf(fmaxf(sc[0][0], sc[0][1]), fmaxf(sc[0][2], sc[0][3])),
                       fmaxf(fmaxf(sc[1][0], sc[1][1]), fmaxf(sc[1][2], sc[1][3])));
    mx16 = fmaxf(mx16, fmaxf(fmaxf(sc[2][0], sc[2][1]), fmaxf(sc[2][2], sc[2][3])));
    mx16 = fmaxf(mx16, fmaxf(fmaxf(sc[3][0], sc[3][1]), fmaxf(sc[3][2], sc[3][3])));
    if (!__all(mx16 <= mrun + 8.f)) {
      float mx = fmaxf(mx16, __shfl_xor(mx16, 16));
      mx = fmaxf(mx, __shfl_xor(mx, 32));
      float mnew = fmaxf(mrun, mx);
      float corr = __builtin_exp2f(mrun - mnew);
      mrun = mnew;
      lrun *= corr;
#pragma unroll
      for (int dt = 0; dt < 8; dt++)
#pragma unroll
        for (int j = 0; j < 4; j++) oacc[dt][j] *= corr;
    }
    float ts = 0.f;
#pragma unroll
    for (int nt = 0; nt < 4; nt++)
#pragma unroll
      for (int j = 0; j < 4; j++) {
        float e = __builtin_exp2f(sc[nt][j] - mrun);
        sc[nt][j] = e;
        ts += e;
      }
    lrun += ts;                                  // per-lane partial; reduced in epilogue

    // P[q=lm][k=16nt+4lg+j] -> LDS as packed bf16 pairs
#pragma unroll
    for (int nt = 0; nt < 4; nt++) {
      unsigned int w0, w1;
      asm("v_cvt_pk_bf16_f32 %0, %1, %2" : "=v"(w0) : "v"(sc[nt][0]), "v"(sc[nt][1]));
      asm("v_cvt_pk_bf16_f32 %0, %1, %2" : "=v"(w1) : "v"(sc[nt][2]), "v"(sc[nt][3]));
      *(unsigned int*)&Ps[wave][lm][nt * 16 + 4 * lg]     = w0;
      *(unsigned int*)&Ps[wave][lm][nt * 16 + 4 * lg + 2] = w1;
    }

    // O^T += V^T · P^T  (A = prefetched V frags, B = Ps row lm)
    __builtin_amdgcn_s_setprio(1);
#pragma unroll
    for (int t = 0; t < 2; t++) {
      bf16x8 pb = *(const bf16x8*)&Ps[wave][lm][t * 32 + lk8];
#pragma unroll
      for (int dt = 0; dt < 8; dt++)
        oacc[dt] = __builtin_amdgcn_mfma_f32_16x16x32_bf16(av[t][dt], pb, oacc[dt], 0, 0, 0);
    }
    __builtin_amdgcn_s_setprio(0);
    __syncthreads();                             // drains gll (issued a phase ago) + LDS
    cur ^= 1;
  }

  // epilogue: reduce l across lane groups, O^T / l -> ob[B,N,H*128]
  lrun += __shfl_xor(lrun, 16);
  lrun += __shfl_xor(lrun, 32);
  float inv = 1.0f / lrun;
  unsigned short* orow = ob + ((b * 1024 + q0 + wave * 16 + lm) * 8 + h) * 128;
#pragma unroll
  for (int dt = 0; dt < 8; dt++) {
#pragma unroll
    for (int pp = 0; pp < 2; pp++) {
      ushort2 o2;
      o2.x = f2bf(oacc[dt][2 * pp]     * inv);
      o2.y = f2bf(oacc[dt][2 * pp + 1] * inv);
      *(ushort2*)&orow[dt * 16 + 4 * lg + 2 * pp] = o2;
    }
  }
}

// ------------- proj GEMM: [16384,1024] @ [1024,128] + bias -> fp32 ----------
// BK=128, gll double-buffered staging, one barrier per K-step.
__global__ __launch_bounds__(256) void k_proj(const unsigned short* __restrict__ ob,
                                              const unsigned short* __restrict__ wpt, // [128][1024]
                                              const float* __restrict__ bproj,
                                              float* __restrict__ out) {
  __shared__ __align__(16) unsigned short Os[2][64][128];
  __shared__ __align__(16) unsigned short Ws2[2][128][128];
  const int m0 = blockIdx.x * 64;
  const int tid = threadIdx.x, wave = tid >> 6, lane = tid & 63;
  const int lm = lane & 15, lg = lane >> 4;
  const int wr = wave >> 1, wc = wave & 1;

  auto stage = [&](int kt, int buf) {
#pragma unroll
    for (int ii = 0; ii < 4; ii++) {             // O tile: 64 rows x 256B
      int row = wave * 16 + ii * 4 + (lane >> 4);
      int c = (lane & 15) ^ (row & 7);
      gll16(ob + (m0 + row) * 1024 + kt * 128 + c * 8, &Os[buf][wave * 16 + ii * 4][0]);
    }
#pragma unroll
    for (int ii = 0; ii < 8; ii++) {             // W tile: 128 rows x 256B
      int row = wave * 32 + ii * 4 + (lane >> 4);
      int c = (lane & 15) ^ (row & 7);
      gll16(wpt + row * 1024 + kt * 128 + c * 8, &Ws2[buf][wave * 32 + ii * 4][0]);
    }
  };

  f32x4 acc[2][4];
#pragma unroll
  for (int i = 0; i < 2; i++)
#pragma unroll
    for (int j = 0; j < 4; j++) acc[i][j] = {0.f, 0.f, 0.f, 0.f};

  stage(0, 0);
  __syncthreads();
  int cur = 0;

  for (int kt = 0; kt < 8; kt++) {
    if (kt < 7) stage(kt + 1, cur ^ 1);
    __builtin_amdgcn_sched_barrier(0);
#pragma unroll
    for (int k32 = 0; k32 < 4; k32++) {
      bf16x8 af[2], bfr[4];
#pragma unroll
      for (int mi = 0; mi < 2; mi++) {
        int row = wr * 32 + mi * 16 + lm;
        af[mi] = *(const bf16x8*)((const char*)&Os[cur][row][0] + ((k32 * 64 + lg * 16) ^ ((lm & 7) << 4)));
      }
#pragma unroll
      for (int ni = 0; ni < 4; ni++) {
        int row = wc * 64 + ni * 16 + lm;
        bfr[ni] = *(const bf16x8*)((const char*)&Ws2[cur][row][0] + ((k32 * 64 + lg * 16) ^ ((lm & 7) << 4)));
      }
#pragma unroll
      for (int mi = 0; mi < 2; mi++)
#pragma unroll
        for (int ni = 0; ni < 4; ni++)
          acc[mi][ni] = __builtin_amdgcn_mfma_f32_16x16x32_bf16(af[mi], bfr[ni], acc[mi][ni], 0, 0, 0);
    }
    __syncthreads();
    cur ^= 1;
  }

#pragma unroll
  for (int mi = 0; mi < 2; mi++)
#pragma unroll
    for (int ni = 0; ni < 4; ni++)
#pragma unroll
      for (int j = 0; j < 4; j++) {
        int m = m0 + wr * 32 + mi * 16 + 4 * (lane >> 4) + j;
        int n = wc * 64 + ni * 16 + lm;
        out[m * 128 + n] = acc[mi][ni][j] + bproj[n];
      }
}

extern "C" void kernel_launch(void* const* d_in, const int* in_sizes, int n_in,
                              void* d_out, int out_size, void* d_ws, size_t ws_size,
                              hipStream_t stream) {
  const float* x     = (const float*)d_in[0];
  const float* gamma = (const float*)d_in[1];
  const float* beta  = (const float*)d_in[2];
  const float* wqkv  = (const float*)d_in[3];
  const float* wproj = (const float*)d_in[4];
  const float* bproj = (const float*)d_in[5];
  float* out = (float*)d_out;

  unsigned short* ws = (unsigned short*)d_ws;
  unsigned short* xb     = ws;                       // 16384*128      = 2,097,152
  unsigned short* wqkvT  = xb + 2097152;             // 3072*128       =   393,216
  unsigned short* wprojT = wqkvT + 393216;           // 128*1024       =   131,072
  unsigned short* qbuf   = wprojT + 131072;          // 16*8*1024*128  = 16,777,216
  unsigned short* kbuf   = qbuf + 16777216;
  unsigned short* vtbuf  = kbuf + 16777216;
  unsigned short* obuf   = vtbuf + 16777216;         // total ~139.5 MB

  hipLaunchKernelGGL(k_ln,         dim3(4096),     dim3(256), 0, stream, x, gamma, beta, xb);
  hipLaunchKernelGGL(k_cast_wqkv,  dim3(48),       dim3(256), 0, stream, wqkv, wqkvT);
  hipLaunchKernelGGL(k_cast_wproj, dim3(8),        dim3(256), 0, stream, wproj, wprojT);
  hipLaunchKernelGGL(k_qkv,        dim3(128, 24),  dim3(256), 0, stream, xb, wqkvT, qbuf, kbuf, vtbuf);
  hipLaunchKernelGGL(k_flash,      dim3(2048),     dim3(256), 0, stream, qbuf, kbuf, vtbuf, obuf);
  hipLaunchKernelGGL(k_proj,       dim3(256),      dim3(256), 0, stream, obuf, wprojT, bproj, out);
}

// Round 5
// 187.689 us; speedup vs baseline: 1.8609x; 1.8609x over previous
//
#include <hip/hip_runtime.h>
#include <hip/hip_bf16.h>

// Problem: B=16, N=1024, EMB=128, H=8, INNER=1024
// out = proj( attention( LN(x) @ Wqkv ) ) + b_proj,  fp32 in/out, bf16-tolerance.

typedef __attribute__((ext_vector_type(8))) short bf16x8;
typedef __attribute__((ext_vector_type(4))) float f32x4;

__device__ __forceinline__ unsigned short f2bf(float f) {
  unsigned int u = __float_as_uint(f);
  u += 0x7FFF + ((u >> 16) & 1);   // round-nearest-even
  return (unsigned short)(u >> 16);
}

// async global->LDS, 16B per lane; LDS dest = wave-uniform base + lane*16
__device__ __forceinline__ void gll16(const void* g, void* l) {
  __builtin_amdgcn_global_load_lds((const __attribute__((address_space(1))) unsigned int*)g,
                                   (__attribute__((address_space(3))) unsigned int*)l, 16, 0, 0);
}

// ---------------- LayerNorm + bf16 cast: one wave per 128-elem row ----------
__global__ __launch_bounds__(256) void k_ln(const float* __restrict__ x,
                                            const float* __restrict__ gamma,
                                            const float* __restrict__ beta,
                                            unsigned short* __restrict__ xb) {
  int row  = blockIdx.x * 4 + (threadIdx.x >> 6);
  int lane = threadIdx.x & 63;
  float2 v = *reinterpret_cast<const float2*>(x + row * 128 + lane * 2);
  float s = v.x + v.y, ss = v.x * v.x + v.y * v.y;
#pragma unroll
  for (int m = 1; m < 64; m <<= 1) { s += __shfl_xor(s, m); ss += __shfl_xor(ss, m); }
  float mu   = s * (1.0f / 128.0f);
  float var  = ss * (1.0f / 128.0f) - mu * mu;
  float rstd = rsqrtf(var + 1e-5f);
  float2 g  = *reinterpret_cast<const float2*>(gamma + lane * 2);
  float2 be = *reinterpret_cast<const float2*>(beta + lane * 2);
  ushort2 o;
  o.x = f2bf((v.x - mu) * rstd * g.x + be.x);
  o.y = f2bf((v.y - mu) * rstd * g.y + be.y);
  *reinterpret_cast<ushort2*>(xb + row * 128 + lane * 2) = o;
}

// ------------- cast + transpose w_qkv [128][3072] -> [3072][128] bf16 -------
__global__ __launch_bounds__(256) void k_cast_wqkv(const float* __restrict__ w,
                                                   unsigned short* __restrict__ wt) {
  __shared__ unsigned short T[128][70];
  const int n0 = blockIdx.x * 64;
  const int tid = threadIdx.x;
#pragma unroll
  for (int i = 0; i < 32; i++) {
    int idx = i * 256 + tid;
    int k = idx >> 6, c = idx & 63;
    T[k][c] = f2bf(w[k * 3072 + n0 + c]);
  }
  __syncthreads();
#pragma unroll
  for (int i = 0; i < 32; i++) {
    int idx = i * 256 + tid;
    int n = idx >> 7, k = idx & 127;
    wt[(n0 + n) * 128 + k] = T[k][n];
  }
}

// ------------- cast + transpose w_proj [1024][128] -> [128][1024] bf16 ------
__global__ __launch_bounds__(256) void k_cast_wproj(const float* __restrict__ w,
                                                    unsigned short* __restrict__ wt) {
  __shared__ unsigned short T[128][134];
  const int k0 = blockIdx.x * 128;
  const int tid = threadIdx.x;
#pragma unroll
  for (int i = 0; i < 64; i++) {
    int idx = i * 256 + tid;
    int r = idx >> 7, c = idx & 127;
    T[r][c] = f2bf(w[(k0 + r) * 128 + c]);
  }
  __syncthreads();
#pragma unroll
  for (int i = 0; i < 64; i++) {
    int idx = i * 256 + tid;
    int c = idx >> 7, r = idx & 127;
    wt[c * 1024 + k0 + r] = T[r][c];
  }
}

// ------------- QKV GEMM: [16384,128] @ [128,3072]; writes Q,K [B,H,N,D], Vt [B,H,D,N]
__global__ __launch_bounds__(256) void k_qkv(const unsigned short* __restrict__ xb,
                                             const unsigned short* __restrict__ wt,  // [3072][128]
                                             unsigned short* __restrict__ qb,
                                             unsigned short* __restrict__ kb,
                                             unsigned short* __restrict__ vtb) {
  __shared__ __align__(16) unsigned short Xs[128][128];
  __shared__ __align__(16) unsigned short Ws[128][128];
  const int m0 = blockIdx.x * 128;
  const int n0 = blockIdx.y * 128;
  const int tid = threadIdx.x, wave = tid >> 6, lane = tid & 63;
  const int lm = lane & 15, lg = lane >> 4;
  const int wr = wave >> 1, wc = wave & 1;

#pragma unroll
  for (int ii = 0; ii < 8; ii++) {
    int row = wave * 32 + ii * 4 + (lane >> 4);
    int c = (lane & 15) ^ (row & 7);
    gll16(xb + (m0 + row) * 128 + c * 8, &Xs[wave * 32 + ii * 4][0]);
    gll16(wt + (n0 + row) * 128 + c * 8, &Ws[wave * 32 + ii * 4][0]);
  }
  __syncthreads();

  f32x4 acc[4][4];
#pragma unroll
  for (int i = 0; i < 4; i++)
#pragma unroll
    for (int j = 0; j < 4; j++) acc[i][j] = {0.f, 0.f, 0.f, 0.f};

#pragma unroll
  for (int k32 = 0; k32 < 4; k32++) {
    bf16x8 af[4], bfr[4];
#pragma unroll
    for (int mi = 0; mi < 4; mi++) {
      int row = wr * 64 + mi * 16 + lm;
      af[mi] = *(const bf16x8*)((const char*)&Xs[row][0] + ((k32 * 64 + lg * 16) ^ ((lm & 7) << 4)));
    }
#pragma unroll
    for (int ni = 0; ni < 4; ni++) {
      int row = wc * 64 + ni * 16 + lm;
      bfr[ni] = *(const bf16x8*)((const char*)&Ws[row][0] + ((k32 * 64 + lg * 16) ^ ((lm & 7) << 4)));
    }
#pragma unroll
    for (int mi = 0; mi < 4; mi++)
#pragma unroll
      for (int ni = 0; ni < 4; ni++)
        acc[mi][ni] = __builtin_amdgcn_mfma_f32_16x16x32_bf16(af[mi], bfr[ni], acc[mi][ni], 0, 0, 0);
  }

  // epilogue: n<1024 -> Q (scaled by (1/32)*log2(e) for exp2 softmax), n<2048 -> K, else V^T
#pragma unroll
  for (int mi = 0; mi < 4; mi++)
#pragma unroll
    for (int ni = 0; ni < 4; ni++)
#pragma unroll
      for (int j = 0; j < 4; j++) {
        int m = m0 + wr * 64 + mi * 16 + 4 * (lane >> 4) + j;
        int n = n0 + wc * 64 + ni * 16 + lm;
        float val = acc[mi][ni][j];
        int bb = m >> 10, seq = m & 1023;
        int sel = n >> 10, r = n & 1023, h = r >> 7, d = r & 127;
        int bh = bb * 8 + h;
        if (sel == 0)      qb[(bh * 1024 + seq) * 128 + d] = f2bf(val * 0.04508422f);
        else if (sel == 1) kb[(bh * 1024 + seq) * 128 + d] = f2bf(val);
        else               vtb[(bh * 128 + d) * 1024 + seq] = f2bf(val);
      }
}

// ------------- flash attention: 32 q/wave, 128 q/block, K+V single-buffer gll
// grid 1024: xcd = bi&7 = bh%8; 8 q-tiles of one bh are consecutive on one XCD.
__global__ __launch_bounds__(256, 3) void k_flash(const unsigned short* __restrict__ qb,
                                                  const unsigned short* __restrict__ kb,
                                                  const unsigned short* __restrict__ vtb,
                                                  unsigned short* __restrict__ ob) {
  __shared__ __align__(16) unsigned short Ks[64][128];    // [key][d], swizzled 16B slots
  __shared__ __align__(16) unsigned short Vts[128][64];   // [d][key], swizzled
  __shared__ __align__(16) unsigned short Ps[4][32][64];  // per-wave P[q][k], swizzled
  const int bi = blockIdx.x;
  const int xcd = bi & 7, g = bi >> 3;                    // g in [0,128)
  const int bh = xcd + 8 * (g >> 3);
  const int q0 = (g & 7) * 128;
  const int tid = threadIdx.x, wave = tid >> 6, lane = tid & 63;
  const int lm = lane & 15, lg = lane >> 4, lk8 = lg * 8;
  const int sw = (lm & 7) << 4;                           // read-side XOR swizzle
  const int b = bh >> 3, h = bh & 7;

  const unsigned short* kbh = kb + bh * 131072;
  const unsigned short* vbh = vtb + bh * 131072;

  // Q^T B-fragments for 2 q-subtiles (q pre-scaled by (1/32)*log2e in k_qkv)
  bf16x8 aq[2][4];
#pragma unroll
  for (int qs = 0; qs < 2; qs++) {
    const unsigned short* qrow = qb + (bh * 1024 + q0 + wave * 32 + qs * 16 + lm) * 128;
#pragma unroll
    for (int kc = 0; kc < 4; kc++) aq[qs][kc] = *(const bf16x8*)(qrow + kc * 32 + lk8);
  }

  f32x4 oacc[2][8];                                       // O^T[d=16dt+4lg+j][q=lm]
#pragma unroll
  for (int qs = 0; qs < 2; qs++)
#pragma unroll
    for (int dt = 0; dt < 8; dt++) oacc[qs][dt] = {0.f, 0.f, 0.f, 0.f};
  float mrun[2] = {-3e38f, -3e38f}, lrun[2] = {0.f, 0.f};

  auto stage = [&](int kt) {
#pragma unroll
    for (int ii = 0; ii < 4; ii++) {            // K: 4 rows x 256B per gll
      int krow = (wave * 4 + ii) * 4 + (lane >> 4);
      int c = (lane & 15) ^ (krow & 7);
      gll16(kbh + (kt * 64 + krow) * 128 + c * 8, &Ks[(wave * 4 + ii) * 4][0]);
    }
#pragma unroll
    for (int ii = 0; ii < 4; ii++) {            // Vt: 8 rows x 128B per gll
      int vrow = (wave * 4 + ii) * 8 + (lane >> 3);
      int c = (lane & 7) ^ (vrow & 7);
      gll16(vbh + vrow * 1024 + kt * 64 + c * 8, &Vts[(wave * 4 + ii) * 8][0]);
    }
  };

  stage(0);
  __syncthreads();

  for (int kt = 0; kt < 16; kt++) {
    // S^T = K · Q^T : lane holds S^T[16nt+4lg+j][q=qs*16+lm] (log2 domain)
    f32x4 sc[2][4];
    __builtin_amdgcn_s_setprio(1);
#pragma unroll
    for (int nt = 0; nt < 4; nt++) {
      f32x4 a0 = {0.f, 0.f, 0.f, 0.f}, a1 = {0.f, 0.f, 0.f, 0.f};
      const char* krowp = (const char*)&Ks[nt * 16 + lm][0];
#pragma unroll
      for (int kc = 0; kc < 4; kc++) {
        bf16x8 ak = *(const bf16x8*)(krowp + ((kc * 64 + lg * 16) ^ sw));
        a0 = __builtin_amdgcn_mfma_f32_16x16x32_bf16(ak, aq[0][kc], a0, 0, 0, 0);
        a1 = __builtin_amdgcn_mfma_f32_16x16x32_bf16(ak, aq[1][kc], a1, 0, 0, 0);
      }
      sc[0][nt] = a0; sc[1][nt] = a1;
    }
    __builtin_amdgcn_s_setprio(0);

    // online softmax per q-subtile, base-2, defer-max (THR=8)
#pragma unroll
    for (int qs = 0; qs < 2; qs++) {
      float mx16 = fmaxf(fmaxf(fmaxf(sc[qs][0][0], sc[qs][0][1]), fmaxf(sc[qs][0][2], sc[qs][0][3])),
                         fmaxf(fmaxf(sc[qs][1][0], sc[qs][1][1]), fmaxf(sc[qs][1][2], sc[qs][1][3])));
      mx16 = fmaxf(mx16, fmaxf(fmaxf(sc[qs][2][0], sc[qs][2][1]), fmaxf(sc[qs][2][2], sc[qs][2][3])));
      mx16 = fmaxf(mx16, fmaxf(fmaxf(sc[qs][3][0], sc[qs][3][1]), fmaxf(sc[qs][3][2], sc[qs][3][3])));
      if (!__all(mx16 <= mrun[qs] + 8.f)) {
        float mx = fmaxf(mx16, __shfl_xor(mx16, 16));
        mx = fmaxf(mx, __shfl_xor(mx, 32));
        float mnew = fmaxf(mrun[qs], mx);
        float corr = __builtin_exp2f(mrun[qs] - mnew);
        mrun[qs] = mnew;
        lrun[qs] *= corr;
#pragma unroll
        for (int dt = 0; dt < 8; dt++)
#pragma unroll
          for (int j = 0; j < 4; j++) oacc[qs][dt][j] *= corr;
      }
      float ts = 0.f;
#pragma unroll
      for (int nt = 0; nt < 4; nt++)
#pragma unroll
        for (int j = 0; j < 4; j++) {
          float e = __builtin_exp2f(sc[qs][nt][j] - mrun[qs]);
          sc[qs][nt][j] = e;
          ts += e;
        }
      lrun[qs] += ts;                            // lane-partial; reduced in epilogue

      // P[q][k] -> LDS (packed bf16 pairs, swizzled): short s at byte 2s ^ sw
      char* psrow = (char*)&Ps[wave][qs * 16 + lm][0];
#pragma unroll
      for (int nt = 0; nt < 4; nt++) {
        unsigned int w0, w1;
        asm("v_cvt_pk_bf16_f32 %0, %1, %2" : "=v"(w0) : "v"(sc[qs][nt][0]), "v"(sc[qs][nt][1]));
        asm("v_cvt_pk_bf16_f32 %0, %1, %2" : "=v"(w1) : "v"(sc[qs][nt][2]), "v"(sc[qs][nt][3]));
        int p0 = (nt * 32 + lg * 8) ^ sw;
        *(unsigned int*)(psrow + p0)     = w0;
        *(unsigned int*)(psrow + p0 + 4) = w1;
      }
    }

    // O^T += V^T · P^T  (V frags shared across both q-subtiles)
    __builtin_amdgcn_s_setprio(1);
#pragma unroll
    for (int t = 0; t < 2; t++) {
      bf16x8 pb0 = *(const bf16x8*)((const char*)&Ps[wave][lm][0]      + ((t * 64 + lg * 16) ^ sw));
      bf16x8 pb1 = *(const bf16x8*)((const char*)&Ps[wave][16 + lm][0] + ((t * 64 + lg * 16) ^ sw));
#pragma unroll
      for (int dt = 0; dt < 8; dt++) {
        bf16x8 av = *(const bf16x8*)((const char*)&Vts[dt * 16 + lm][0] + ((t * 64 + lg * 16) ^ sw));
        oacc[0][dt] = __builtin_amdgcn_mfma_f32_16x16x32_bf16(av, pb0, oacc[0][dt], 0, 0, 0);
        oacc[1][dt] = __builtin_amdgcn_mfma_f32_16x16x32_bf16(av, pb1, oacc[1][dt], 0, 0, 0);
      }
    }
    __builtin_amdgcn_s_setprio(0);

    __syncthreads();                             // all reads of kt tiles done
    if (kt < 15) {
      stage(kt + 1);                             // overwrite single buffers
      __syncthreads();                           // gll drained (vmcnt in barrier)
    }
  }

  // epilogue: reduce l across lane groups, O^T / l -> ob[B,N,H*128]
#pragma unroll
  for (int qs = 0; qs < 2; qs++) {
    float l = lrun[qs];
    l += __shfl_xor(l, 16);
    l += __shfl_xor(l, 32);
    float inv = 1.0f / l;
    unsigned short* orow = ob + ((b * 1024 + q0 + wave * 32 + qs * 16 + lm) * 8 + h) * 128;
#pragma unroll
    for (int dt = 0; dt < 8; dt++) {
#pragma unroll
      for (int pp = 0; pp < 2; pp++) {
        ushort2 o2;
        o2.x = f2bf(oacc[qs][dt][2 * pp]     * inv);
        o2.y = f2bf(oacc[qs][dt][2 * pp + 1] * inv);
        *(ushort2*)&orow[dt * 16 + 4 * lg + 2 * pp] = o2;
      }
    }
  }
}

// ------------- proj GEMM: [16384,1024] @ [1024,128] + bias -> fp32 ----------
__global__ __launch_bounds__(256) void k_proj(const unsigned short* __restrict__ ob,
                                              const unsigned short* __restrict__ wpt, // [128][1024]
                                              const float* __restrict__ bproj,
                                              float* __restrict__ out) {
  __shared__ __align__(16) unsigned short Os[2][64][128];
  __shared__ __align__(16) unsigned short Ws2[2][128][128];
  const int m0 = blockIdx.x * 64;
  const int tid = threadIdx.x, wave = tid >> 6, lane = tid & 63;
  const int lm = lane & 15, lg = lane >> 4;
  const int wr = wave >> 1, wc = wave & 1;

  auto stage = [&](int kt, int buf) {
#pragma unroll
    for (int ii = 0; ii < 4; ii++) {             // O tile: 64 rows x 256B
      int row = wave * 16 + ii * 4 + (lane >> 4);
      int c = (lane & 15) ^ (row & 7);
      gll16(ob + (m0 + row) * 1024 + kt * 128 + c * 8, &Os[buf][wave * 16 + ii * 4][0]);
    }
#pragma unroll
    for (int ii = 0; ii < 8; ii++) {             // W tile: 128 rows x 256B
      int row = wave * 32 + ii * 4 + (lane >> 4);
      int c = (lane & 15) ^ (row & 7);
      gll16(wpt + row * 1024 + kt * 128 + c * 8, &Ws2[buf][wave * 32 + ii * 4][0]);
    }
  };

  f32x4 acc[2][4];
#pragma unroll
  for (int i = 0; i < 2; i++)
#pragma unroll
    for (int j = 0; j < 4; j++) acc[i][j] = {0.f, 0.f, 0.f, 0.f};

  stage(0, 0);
  __syncthreads();
  int cur = 0;

  for (int kt = 0; kt < 8; kt++) {
    if (kt < 7) stage(kt + 1, cur ^ 1);
    __builtin_amdgcn_sched_barrier(0);
#pragma unroll
    for (int k32 = 0; k32 < 4; k32++) {
      bf16x8 af[2], bfr[4];
#pragma unroll
      for (int mi = 0; mi < 2; mi++) {
        int row = wr * 32 + mi * 16 + lm;
        af[mi] = *(const bf16x8*)((const char*)&Os[cur][row][0] + ((k32 * 64 + lg * 16) ^ ((lm & 7) << 4)));
      }
#pragma unroll
      for (int ni = 0; ni < 4; ni++) {
        int row = wc * 64 + ni * 16 + lm;
        bfr[ni] = *(const bf16x8*)((const char*)&Ws2[cur][row][0] + ((k32 * 64 + lg * 16) ^ ((lm & 7) << 4)));
      }
#pragma unroll
      for (int mi = 0; mi < 2; mi++)
#pragma unroll
        for (int ni = 0; ni < 4; ni++)
          acc[mi][ni] = __builtin_amdgcn_mfma_f32_16x16x32_bf16(af[mi], bfr[ni], acc[mi][ni], 0, 0, 0);
    }
    __syncthreads();
    cur ^= 1;
  }

#pragma unroll
  for (int mi = 0; mi < 2; mi++)
#pragma unroll
    for (int ni = 0; ni < 4; ni++)
#pragma unroll
      for (int j = 0; j < 4; j++) {
        int m = m0 + wr * 32 + mi * 16 + 4 * (lane >> 4) + j;
        int n = wc * 64 + ni * 16 + lm;
        out[m * 128 + n] = acc[mi][ni][j] + bproj[n];
      }
}

extern "C" void kernel_launch(void* const* d_in, const int* in_sizes, int n_in,
                              void* d_out, int out_size, void* d_ws, size_t ws_size,
                              hipStream_t stream) {
  const float* x     = (const float*)d_in[0];
  const float* gamma = (const float*)d_in[1];
  const float* beta  = (const float*)d_in[2];
  const float* wqkv  = (const float*)d_in[3];
  const float* wproj = (const float*)d_in[4];
  const float* bproj = (const float*)d_in[5];
  float* out = (float*)d_out;

  unsigned short* ws = (unsigned short*)d_ws;
  unsigned short* xb     = ws;                       // 16384*128      = 2,097,152
  unsigned short* wqkvT  = xb + 2097152;             // 3072*128       =   393,216
  unsigned short* wprojT = wqkvT + 393216;           // 128*1024       =   131,072
  unsigned short* qbuf   = wprojT + 131072;          // 16*8*1024*128  = 16,777,216
  unsigned short* kbuf   = qbuf + 16777216;
  unsigned short* vtbuf  = kbuf + 16777216;
  unsigned short* obuf   = vtbuf + 16777216;         // total ~139.5 MB

  hipLaunchKernelGGL(k_ln,         dim3(4096),     dim3(256), 0, stream, x, gamma, beta, xb);
  hipLaunchKernelGGL(k_cast_wqkv,  dim3(48),       dim3(256), 0, stream, wqkv, wqkvT);
  hipLaunchKernelGGL(k_cast_wproj, dim3(8),        dim3(256), 0, stream, wproj, wprojT);
  hipLaunchKernelGGL(k_qkv,        dim3(128, 24),  dim3(256), 0, stream, xb, wqkvT, qbuf, kbuf, vtbuf);
  hipLaunchKernelGGL(k_flash,      dim3(1024),     dim3(256), 0, stream, qbuf, kbuf, vtbuf, obuf);
  hipLaunchKernelGGL(k_proj,       dim3(256),      dim3(256), 0, stream, obuf, wprojT, bproj, out);
}